// Round 2
// baseline (148.742 us; speedup 1.0000x reference)
//
#include <hip/hip_runtime.h>
#include <float.h>

#define NB 64
#define NS 512
#define NH 768
#define NL 32
#define NK 8

#define OFF_START 0
#define OFF_END   (NB*NS)
#define OFF_SPANS (2*NB*NS)
#define OFF_NSP   (2*NB*NS + NB*NL)
#define OFF_SOH   (2*NB*NS + NB*NL + NB*9)
#define OFF_EOH   (3*NB*NS + NB*NL + NB*9)
#define OFF_LAB   (4*NB*NS + NB*NL + NB*9)

// ---------------- Kernel A: start/end logits (memory-bound pass) ----------------
__global__ __launch_bounds__(256) void kA(const float* __restrict__ T,
                                          const float* __restrict__ Ws,
                                          const float* __restrict__ We,
                                          const float* __restrict__ bs,
                                          const float* __restrict__ be,
                                          float* __restrict__ out) {
    int row  = blockIdx.x * 4 + (threadIdx.x >> 6);   // (b*512+s)
    int lane = threadIdx.x & 63;
    const float4* p   = (const float4*)(T + (size_t)row * NH);
    const float4* w4s = (const float4*)Ws;
    const float4* w4e = (const float4*)We;
    float accs = 0.f, acce = 0.f;
#pragma unroll
    for (int c = 0; c < 3; ++c) {
        float4 t = p[lane + c * 64];
        float4 a = w4s[lane + c * 64];
        float4 b = w4e[lane + c * 64];
        accs += t.x * a.x + t.y * a.y + t.z * a.z + t.w * a.w;
        acce += t.x * b.x + t.y * b.y + t.z * b.z + t.w * b.w;
    }
#pragma unroll
    for (int off = 32; off > 0; off >>= 1) {
        accs += __shfl_down(accs, off);
        acce += __shfl_down(acce, off);
    }
    if (lane == 0) {
        out[OFF_START + row] = accs + bs[0];
        out[OFF_END   + row] = acce + be[0];
    }
}

// block-wide argmax over 512 LDS floats, tie -> lower index
__device__ void argmax512(const float* vals, float* redv, int* redi, int tid, int* out) {
    float v1 = vals[tid], v2 = vals[tid + 256];
    float bv; int bi;
    if (v2 > v1) { bv = v2; bi = tid + 256; } else { bv = v1; bi = tid; }
    redv[tid] = bv; redi[tid] = bi;
    __syncthreads();
    for (int off = 128; off > 0; off >>= 1) {
        if (tid < off) {
            float ov = redv[tid + off]; int oi = redi[tid + off];
            if (ov > redv[tid] || (ov == redv[tid] && oi < redi[tid])) {
                redv[tid] = ov; redi[tid] = oi;
            }
        }
        __syncthreads();
    }
    if (tid == 0) *out = redi[0];
    __syncthreads();
}

// ---------------- Kernel B: per-sample heads, top-k, greedy merge ----------------
__global__ __launch_bounds__(256) void kB(const float* __restrict__ seq_rep,
                                          const float* __restrict__ W_nspans,
                                          const float* __restrict__ b_nspans,
                                          const float* __restrict__ W_span,
                                          const float* __restrict__ b_span,
                                          float* __restrict__ out,
                                          int* __restrict__ wsI,
                                          float* __restrict__ wsF) {
    int b = blockIdx.x, tid = threadIdx.x;
    __shared__ float sv[NH];
    __shared__ float rs[NS], re[NS];
    __shared__ float redv[256];
    __shared__ int   redi[256];
    __shared__ float part[6][41];   // 6 h-groups of 128; 6*41=246 <= 256 threads
    __shared__ float fl[NL], nsp[9];
    __shared__ int   topS[NK], topE[NK], amx;

    for (int i = tid; i < NH; i += 256) sv[i] = seq_rep[b * NH + i];
    for (int i = tid; i < NS; i += 256) {
        rs[i] = out[OFF_START + b * NS + i];
        re[i] = out[OFF_END   + b * NS + i];
    }
    __syncthreads();

    // fused GEMV: 41 outputs (32 span-labels + 9 nspans), 6-way h split of 128 each
    if (tid < 246) {
        int g = tid / 41, l = tid % 41;
        int h0 = g * 128;
        float acc = 0.f;
        if (l < 32) {
            for (int h = h0; h < h0 + 128; ++h) acc += sv[h] * W_span[h * NL + l];
        } else {
            int j = l - 32;
            for (int h = h0; h < h0 + 128; ++h) acc += sv[h] * W_nspans[h * 9 + j];
        }
        part[g][l] = acc;
    }
    __syncthreads();
    if (tid < 41) {
        float a = 0.f;
        for (int g = 0; g < 6; ++g) a += part[g][tid];
        if (tid < 32) fl[tid] = a + b_span[tid];
        else          nsp[tid - 32] = a + b_nspans[tid - 32];
    }
    __syncthreads();

    // destructive top-8 (desc value, stable ties) on raw logits (sigmoid monotone)
    for (int r = 0; r < NK; ++r) {
        argmax512(rs, redv, redi, tid, &amx);
        if (tid == 0) { topS[r] = amx; rs[amx] = -FLT_MAX; }
        __syncthreads();
    }
    for (int r = 0; r < NK; ++r) {
        argmax512(re, redv, redi, tid, &amx);
        if (tid == 0) { topE[r] = amx; re[amx] = -FLT_MAX; }
        __syncthreads();
    }

    if (tid == 0) {
        // n_spans = argmax over 9 (tie -> lowest index)
        int ns = 0; float bv = nsp[0];
        for (int j = 1; j < 9; ++j) if (nsp[j] > bv) { bv = nsp[j]; ns = j; }

        int ss[NK], es[NK];
        for (int i = 0; i < NK; ++i) {
            ss[i] = (i < ns) ? topS[i] : NS;
            es[i] = (i < ns) ? topE[i] : NS;
        }
        // insertion sort ascending
        for (int i = 1; i < NK; ++i) {
            int v = ss[i], j = i - 1;
            while (j >= 0 && ss[j] > v) { ss[j + 1] = ss[j]; --j; }
            ss[j + 1] = v;
        }
        for (int i = 1; i < NK; ++i) {
            int v = es[i], j = i - 1;
            while (j >= 0 && es[j] > v) { es[j + 1] = es[j]; --j; }
            es[j + 1] = v;
        }
        // faithful greedy merge (matches the while_loop body semantics)
        int sa[NK], ea[NK];
        for (int i = 0; i < NK; ++i) { sa[i] = 0; ea[i] = 0; }
        int si = 0, ei = 0, nrem = ns, last = 0, cnt = 0;
        while (nrem > 0 && si < ns && ei < ns) {
            int s = ss[si], e = es[ei];
            bool take = (e > s) && (s >= last);
            if (take) { sa[cnt] = s; ea[cnt] = e; last = e; ++cnt; --nrem; }
            if (e > s) ++si;
            if (take || e <= s) ++ei;
        }
        // arg_full (labels_single)
        int af = 0; float fv = fl[0];
        for (int l = 1; l < NL; ++l) if (fl[l] > fv) { fv = fl[l]; af = l; }

        int* W = wsI + b * 32;
        W[0] = ns; W[1] = cnt; W[2] = af; W[3] = topS[0]; W[4] = topE[0];
        for (int i = 0; i < NK; ++i) { W[5 + i] = sa[i]; W[13 + i] = ea[i]; }
    }
    __syncthreads();
    if (tid < 9)  out[OFF_NSP + b * 9 + tid] = nsp[tid];
    if (tid < 32) wsF[b * 32 + tid] = fl[tid];
}

// ---------------- Kernel C: span mean vectors + span logits ----------------
__global__ __launch_bounds__(256) void kC(const float* __restrict__ T,
                                          const float* __restrict__ W_span,
                                          const float* __restrict__ b_span,
                                          const int* __restrict__ wsI,
                                          float* __restrict__ wsLG) {
    int b = blockIdx.x >> 3, k = blockIdx.x & 7, tid = threadIdx.x;
    const int* W = wsI + b * 32;
    int ns = W[0], cnt = W[1];
    if (ns <= 1 || k >= cnt) return;
    int s = W[5 + k], e = W[13 + k];

    __shared__ float vec[NH];
    __shared__ float pl[8][32];

    float a0 = 0.f, a1 = 0.f, a2 = 0.f;
    const float* Tb = T + (size_t)b * NS * NH;
    for (int r = s; r < e; ++r) {
        const float* p = Tb + (size_t)r * NH + tid;
        a0 += p[0]; a1 += p[256]; a2 += p[512];
    }
    float len = (float)(e - s);   // take requires e > s, so len >= 1
    vec[tid]       = a0 / len;
    vec[tid + 256] = a1 / len;
    vec[tid + 512] = a2 / len;
    __syncthreads();

    int g = tid >> 5, l = tid & 31;
    float acc = 0.f;
    int h0 = g * 96;
    for (int h = h0; h < h0 + 96; ++h) acc += vec[h] * W_span[h * NL + l];
    pl[g][l] = acc;
    __syncthreads();
    if (tid < 32) {
        float a = b_span[tid];
        for (int gg = 0; gg < 8; ++gg) a += pl[gg][tid];
        wsLG[(b * NK + k) * NL + tid] = a;
    }
}

// ---------------- Kernel D: assemble spans/labels/one-hots ----------------
__global__ __launch_bounds__(512) void kD(const int* __restrict__ wsI,
                                          const float* __restrict__ wsF,
                                          const float* __restrict__ wsLG,
                                          float* __restrict__ out) {
    int b = blockIdx.x, t = threadIdx.x;
    const int* W = wsI + b * 32;
    int ns = W[0], cnt = W[1], af = W[2], as_ = W[3], ae_ = W[4];
    bool multi = ns > 1;
    __shared__ int   sa[NK], ea[NK], sl[NK];
    __shared__ float lgs[NK][NL];
    if (t < NK) { sa[t] = W[5 + t]; ea[t] = W[13 + t]; }
    __syncthreads();
    if (t < NK) {
        if (multi && t < cnt) {
            const float* Lp = wsLG + (b * NK + t) * NL;
            float bv = Lp[0]; int bi = 0;
            for (int l = 0; l < NL; ++l) {
                lgs[t][l] = Lp[l];
                if (Lp[l] > bv) { bv = Lp[l]; bi = l; }
            }
            sl[t] = bi;
        } else sl[t] = -1;
    }
    __syncthreads();
    if (t < NL) {
        float sp, lb;
        if (multi) {
            float mx = 0.f;
            if (cnt > 0) {
                mx = -FLT_MAX;
                for (int k = 0; k < cnt; ++k) mx = fmaxf(mx, lgs[k][t]);
            }
            sp = mx;
            lb = 0.f;
            for (int k = 0; k < cnt; ++k) if (sl[k] == t) lb = 1.f;
        } else {
            sp = wsF[b * NL + t];
            lb = (t == af) ? 1.f : 0.f;
        }
        out[OFF_SPANS + b * NL + t] = sp;
        out[OFF_LAB   + b * NL + t] = lb;
    }
    {
        float svv = 0.f, evv = 0.f;
        if (multi) {
            for (int k = 0; k < cnt; ++k) {
                if (sa[k] == t) svv = 1.f;
                if (ea[k] == t) evv = 1.f;
            }
        } else {
            svv = (t == as_) ? 1.f : 0.f;
            evv = (t == ae_) ? 1.f : 0.f;
        }
        out[OFF_SOH + b * NS + t] = svv;
        out[OFF_EOH + b * NS + t] = evv;
    }
}

extern "C" void kernel_launch(void* const* d_in, const int* in_sizes, int n_in,
                              void* d_out, int out_size, void* d_ws, size_t ws_size,
                              hipStream_t stream) {
    const float* tokens   = (const float*)d_in[0];
    const float* seq_rep  = (const float*)d_in[1];
    const float* W_start  = (const float*)d_in[2];
    const float* b_start  = (const float*)d_in[3];
    const float* W_end    = (const float*)d_in[4];
    const float* b_end    = (const float*)d_in[5];
    const float* W_nspans = (const float*)d_in[6];
    const float* b_nspans = (const float*)d_in[7];
    const float* W_span   = (const float*)d_in[8];
    const float* b_span   = (const float*)d_in[9];
    float* out = (float*)d_out;

    int*   wsI  = (int*)d_ws;                                    // 64*32 ints
    float* wsF  = (float*)((char*)d_ws + NB * 32 * sizeof(int)); // 64*32 floats (full_seq rows)
    float* wsLG = (float*)((char*)d_ws + NB * 32 * sizeof(int) + NB * NL * sizeof(float)); // 64*8*32

    kA<<<(NB * NS) / 4, 256, 0, stream>>>(tokens, W_start, W_end, b_start, b_end, out);
    kB<<<NB, 256, 0, stream>>>(seq_rep, W_nspans, b_nspans, W_span, b_span, out, wsI, wsF);
    kC<<<NB * NK, 256, 0, stream>>>(tokens, W_span, b_span, wsI, wsLG);
    kD<<<NB, 512, 0, stream>>>(wsI, wsF, wsLG, out);
}

// Round 3
// 74.915 us; speedup vs baseline: 1.9855x; 1.9855x over previous
//
#include <hip/hip_runtime.h>
#include <float.h>

#define NB 64
#define NS 512
#define NH 768
#define NL 32
#define NK 8

#define OFF_START 0
#define OFF_END   (NB*NS)
#define OFF_SPANS (2*NB*NS)
#define OFF_NSP   (2*NB*NS + NB*NL)
#define OFF_SOH   (2*NB*NS + NB*NL + NB*9)
#define OFF_EOH   (3*NB*NS + NB*NL + NB*9)
#define OFF_LAB   (4*NB*NS + NB*NL + NB*9)

// ---------------- Kernel A: start/end logits (memory-bound pass) ----------------
__global__ __launch_bounds__(256) void kA(const float* __restrict__ T,
                                          const float* __restrict__ Ws,
                                          const float* __restrict__ We,
                                          const float* __restrict__ bs,
                                          const float* __restrict__ be,
                                          float* __restrict__ out) {
    int row  = blockIdx.x * 4 + (threadIdx.x >> 6);   // (b*512+s)
    int lane = threadIdx.x & 63;
    const float4* p   = (const float4*)(T + (size_t)row * NH);
    const float4* w4s = (const float4*)Ws;
    const float4* w4e = (const float4*)We;
    float accs = 0.f, acce = 0.f;
#pragma unroll
    for (int c = 0; c < 3; ++c) {
        float4 t = p[lane + c * 64];
        float4 a = w4s[lane + c * 64];
        float4 b = w4e[lane + c * 64];
        accs += t.x * a.x + t.y * a.y + t.z * a.z + t.w * a.w;
        acce += t.x * b.x + t.y * b.y + t.z * b.z + t.w * b.w;
    }
#pragma unroll
    for (int off = 32; off > 0; off >>= 1) {
        accs += __shfl_down(accs, off);
        acce += __shfl_down(acce, off);
    }
    if (lane == 0) {
        out[OFF_START + row] = accs + bs[0];
        out[OFF_END   + row] = acce + be[0];
    }
}

// block-wide argmax over 512 LDS floats, tie -> lower index. 3 barriers.
__device__ void argmax512(const float* vals, float* redv, int* redi, int tid, int* outIdx) {
    float v1 = vals[tid], v2 = vals[tid + 256];
    float bv; int bi;
    if (v2 > v1) { bv = v2; bi = tid + 256; } else { bv = v1; bi = tid; }
    redv[tid] = bv; redi[tid] = bi;
    __syncthreads();
    if (tid < 128) {
        float ov = redv[tid + 128]; int oi = redi[tid + 128];
        if (ov > redv[tid] || (ov == redv[tid] && oi < redi[tid])) {
            redv[tid] = ov; redi[tid] = oi;
        }
    }
    __syncthreads();
    if (tid < 64) {
        float v = redv[tid]; int i = redi[tid];
        float ov = redv[tid + 64]; int oi = redi[tid + 64];
        if (ov > v || (ov == v && oi < i)) { v = ov; i = oi; }
#pragma unroll
        for (int off = 32; off > 0; off >>= 1) {
            float sv = __shfl_down(v, off);
            int   si = __shfl_down(i, off);
            if (sv > v || (sv == v && si < i)) { v = sv; i = si; }
        }
        if (tid == 0) *outIdx = i;
    }
    __syncthreads();
}

// ---------------- Kernel B: per-sample heads, top-k, greedy merge ----------------
__global__ __launch_bounds__(256) void kB(const float* __restrict__ seq_rep,
                                          const float* __restrict__ W_nspans,
                                          const float* __restrict__ b_nspans,
                                          const float* __restrict__ W_span,
                                          const float* __restrict__ b_span,
                                          float* __restrict__ out,
                                          int* __restrict__ wsI,
                                          float* __restrict__ wsF) {
    int b = blockIdx.x, tid = threadIdx.x;
    __shared__ float sv[NH];
    __shared__ float rs[NS], re[NS];
    __shared__ float redv[256];
    __shared__ int   redi[256];
    __shared__ float part[6][41];   // 6 h-groups of 128; 6*41=246 <= 256 threads
    __shared__ float fl[NL], nsp[9];
    __shared__ int   topS[NK], topE[NK], amx;

    for (int i = tid; i < NH; i += 256) sv[i] = seq_rep[b * NH + i];
    for (int i = tid; i < NS; i += 256) {
        rs[i] = out[OFF_START + b * NS + i];
        re[i] = out[OFF_END   + b * NS + i];
    }
    __syncthreads();

    // fused GEMV: 41 outputs (32 span-labels + 9 nspans), 6-way h split of 128 each
    if (tid < 246) {
        int g = tid / 41, l = tid % 41;
        int h0 = g * 128;
        float acc = 0.f;
        if (l < 32) {
            for (int h = h0; h < h0 + 128; ++h) acc += sv[h] * W_span[h * NL + l];
        } else {
            int j = l - 32;
            for (int h = h0; h < h0 + 128; ++h) acc += sv[h] * W_nspans[h * 9 + j];
        }
        part[g][l] = acc;
    }
    __syncthreads();
    if (tid < 41) {
        float a = 0.f;
        for (int g = 0; g < 6; ++g) a += part[g][tid];
        if (tid < 32) fl[tid] = a + b_span[tid];
        else          nsp[tid - 32] = a + b_nspans[tid - 32];
    }
    __syncthreads();

    // destructive top-8 (desc value, stable ties) on raw logits (sigmoid monotone)
    for (int r = 0; r < NK; ++r) {
        argmax512(rs, redv, redi, tid, &amx);
        if (tid == 0) { topS[r] = amx; rs[amx] = -FLT_MAX; }
        __syncthreads();
    }
    for (int r = 0; r < NK; ++r) {
        argmax512(re, redv, redi, tid, &amx);
        if (tid == 0) { topE[r] = amx; re[amx] = -FLT_MAX; }
        __syncthreads();
    }

    if (tid == 0) {
        // n_spans = argmax over 9 (tie -> lowest index)
        int ns = 0; float bv = nsp[0];
        for (int j = 1; j < 9; ++j) if (nsp[j] > bv) { bv = nsp[j]; ns = j; }

        int ss[NK], es[NK];
        for (int i = 0; i < NK; ++i) {
            ss[i] = (i < ns) ? topS[i] : NS;
            es[i] = (i < ns) ? topE[i] : NS;
        }
        // insertion sort ascending
        for (int i = 1; i < NK; ++i) {
            int v = ss[i], j = i - 1;
            while (j >= 0 && ss[j] > v) { ss[j + 1] = ss[j]; --j; }
            ss[j + 1] = v;
        }
        for (int i = 1; i < NK; ++i) {
            int v = es[i], j = i - 1;
            while (j >= 0 && es[j] > v) { es[j + 1] = es[j]; --j; }
            es[j + 1] = v;
        }
        // faithful greedy merge (matches the while_loop body semantics)
        int sa[NK], ea[NK];
        for (int i = 0; i < NK; ++i) { sa[i] = 0; ea[i] = 0; }
        int si = 0, ei = 0, nrem = ns, last = 0, cnt = 0;
        while (nrem > 0 && si < ns && ei < ns) {
            int s = ss[si], e = es[ei];
            bool take = (e > s) && (s >= last);
            if (take) { sa[cnt] = s; ea[cnt] = e; last = e; ++cnt; --nrem; }
            if (e > s) ++si;
            if (take || e <= s) ++ei;
        }
        // arg_full (labels_single)
        int af = 0; float fv = fl[0];
        for (int l = 1; l < NL; ++l) if (fl[l] > fv) { fv = fl[l]; af = l; }

        int* W = wsI + b * 32;
        W[0] = ns; W[1] = cnt; W[2] = af; W[3] = topS[0]; W[4] = topE[0];
        for (int i = 0; i < NK; ++i) { W[5 + i] = sa[i]; W[13 + i] = ea[i]; }
    }
    __syncthreads();
    if (tid < 9)  out[OFF_NSP + b * 9 + tid] = nsp[tid];
    if (tid < 32) wsF[b * 32 + tid] = fl[tid];
}

// ---------------- Kernel C: span mean vectors + span logits ----------------
// 4 waves split rows round-robin; float4 loads, 2x unroll for ILP; LDS reduce.
__global__ __launch_bounds__(256) void kC(const float* __restrict__ T,
                                          const float* __restrict__ W_span,
                                          const float* __restrict__ b_span,
                                          const int* __restrict__ wsI,
                                          float* __restrict__ wsLG) {
    int b = blockIdx.x >> 3, k = blockIdx.x & 7, tid = threadIdx.x;
    const int* W = wsI + b * 32;
    int ns = W[0], cnt = W[1];
    if (ns <= 1 || k >= cnt) return;   // uniform per block
    int s = W[5 + k], e = W[13 + k];

    __shared__ float4 sm4[4][192];
    __shared__ float  vec[NH];
    __shared__ float  pl[8][32];

    int wave = tid >> 6, lane = tid & 63;
    float4 a0 = make_float4(0.f, 0.f, 0.f, 0.f), a1 = a0, a2 = a0;
    const float4* Tb = (const float4*)(T + (size_t)b * NS * NH);

    int r = s + wave;
    for (; r + 4 < e; r += 8) {
        const float4* p = Tb + (size_t)r * 192 + lane;
        const float4* q = Tb + (size_t)(r + 4) * 192 + lane;
        float4 x0 = p[0], x1 = p[64], x2 = p[128];
        float4 y0 = q[0], y1 = q[64], y2 = q[128];
        a0.x += x0.x + y0.x; a0.y += x0.y + y0.y; a0.z += x0.z + y0.z; a0.w += x0.w + y0.w;
        a1.x += x1.x + y1.x; a1.y += x1.y + y1.y; a1.z += x1.z + y1.z; a1.w += x1.w + y1.w;
        a2.x += x2.x + y2.x; a2.y += x2.y + y2.y; a2.z += x2.z + y2.z; a2.w += x2.w + y2.w;
    }
    if (r < e) {
        const float4* p = Tb + (size_t)r * 192 + lane;
        float4 x0 = p[0], x1 = p[64], x2 = p[128];
        a0.x += x0.x; a0.y += x0.y; a0.z += x0.z; a0.w += x0.w;
        a1.x += x1.x; a1.y += x1.y; a1.z += x1.z; a1.w += x1.w;
        a2.x += x2.x; a2.y += x2.y; a2.z += x2.z; a2.w += x2.w;
    }
    sm4[wave][lane]       = a0;
    sm4[wave][lane + 64]  = a1;
    sm4[wave][lane + 128] = a2;
    __syncthreads();

    if (tid < 192) {
        float inv = 1.f / (float)(e - s);   // take requires e > s
        float4 u0 = sm4[0][tid], u1 = sm4[1][tid], u2 = sm4[2][tid], u3 = sm4[3][tid];
        float4 v;
        v.x = (u0.x + u1.x + u2.x + u3.x) * inv;
        v.y = (u0.y + u1.y + u2.y + u3.y) * inv;
        v.z = (u0.z + u1.z + u2.z + u3.z) * inv;
        v.w = (u0.w + u1.w + u2.w + u3.w) * inv;
        ((float4*)vec)[tid] = v;
    }
    __syncthreads();

    int g = tid >> 5, l = tid & 31;
    float acc = 0.f;
    int h0 = g * 96;
    for (int h = h0; h < h0 + 96; ++h) acc += vec[h] * W_span[h * NL + l];
    pl[g][l] = acc;
    __syncthreads();
    if (tid < 32) {
        float a = b_span[tid];
        for (int gg = 0; gg < 8; ++gg) a += pl[gg][tid];
        wsLG[(b * NK + k) * NL + tid] = a;
    }
}

// ---------------- Kernel D: assemble spans/labels/one-hots ----------------
__global__ __launch_bounds__(512) void kD(const int* __restrict__ wsI,
                                          const float* __restrict__ wsF,
                                          const float* __restrict__ wsLG,
                                          float* __restrict__ out) {
    int b = blockIdx.x, t = threadIdx.x;
    const int* W = wsI + b * 32;
    int ns = W[0], cnt = W[1], af = W[2], as_ = W[3], ae_ = W[4];
    bool multi = ns > 1;
    __shared__ int   sa[NK], ea[NK], sl[NK];
    __shared__ float lgs[NK][NL];
    if (t < NK) { sa[t] = W[5 + t]; ea[t] = W[13 + t]; }
    __syncthreads();
    if (t < NK) {
        if (multi && t < cnt) {
            const float* Lp = wsLG + (b * NK + t) * NL;
            float bv = Lp[0]; int bi = 0;
            for (int l = 0; l < NL; ++l) {
                lgs[t][l] = Lp[l];
                if (Lp[l] > bv) { bv = Lp[l]; bi = l; }
            }
            sl[t] = bi;
        } else sl[t] = -1;
    }
    __syncthreads();
    if (t < NL) {
        float sp, lb;
        if (multi) {
            float mx = 0.f;
            if (cnt > 0) {
                mx = -FLT_MAX;
                for (int k = 0; k < cnt; ++k) mx = fmaxf(mx, lgs[k][t]);
            }
            sp = mx;
            lb = 0.f;
            for (int k = 0; k < cnt; ++k) if (sl[k] == t) lb = 1.f;
        } else {
            sp = wsF[b * NL + t];
            lb = (t == af) ? 1.f : 0.f;
        }
        out[OFF_SPANS + b * NL + t] = sp;
        out[OFF_LAB   + b * NL + t] = lb;
    }
    {
        float svv = 0.f, evv = 0.f;
        if (multi) {
            for (int k = 0; k < cnt; ++k) {
                if (sa[k] == t) svv = 1.f;
                if (ea[k] == t) evv = 1.f;
            }
        } else {
            svv = (t == as_) ? 1.f : 0.f;
            evv = (t == ae_) ? 1.f : 0.f;
        }
        out[OFF_SOH + b * NS + t] = svv;
        out[OFF_EOH + b * NS + t] = evv;
    }
}

extern "C" void kernel_launch(void* const* d_in, const int* in_sizes, int n_in,
                              void* d_out, int out_size, void* d_ws, size_t ws_size,
                              hipStream_t stream) {
    const float* tokens   = (const float*)d_in[0];
    const float* seq_rep  = (const float*)d_in[1];
    const float* W_start  = (const float*)d_in[2];
    const float* b_start  = (const float*)d_in[3];
    const float* W_end    = (const float*)d_in[4];
    const float* b_end    = (const float*)d_in[5];
    const float* W_nspans = (const float*)d_in[6];
    const float* b_nspans = (const float*)d_in[7];
    const float* W_span   = (const float*)d_in[8];
    const float* b_span   = (const float*)d_in[9];
    float* out = (float*)d_out;

    int*   wsI  = (int*)d_ws;                                    // 64*32 ints
    float* wsF  = (float*)((char*)d_ws + NB * 32 * sizeof(int)); // 64*32 floats (full_seq rows)
    float* wsLG = (float*)((char*)d_ws + NB * 32 * sizeof(int) + NB * NL * sizeof(float)); // 64*8*32

    kA<<<(NB * NS) / 4, 256, 0, stream>>>(tokens, W_start, W_end, b_start, b_end, out);
    kB<<<NB, 256, 0, stream>>>(seq_rep, W_nspans, b_nspans, W_span, b_span, out, wsI, wsF);
    kC<<<NB * NK, 256, 0, stream>>>(tokens, W_span, b_span, wsI, wsLG);
    kD<<<NB, 512, 0, stream>>>(wsI, wsF, wsLG, out);
}

// Round 4
// 65.110 us; speedup vs baseline: 2.2845x; 1.1506x over previous
//
#include <hip/hip_runtime.h>
#include <float.h>

#define NB 64
#define NS 512
#define NH 768
#define NL 32
#define NK 8

#define OFF_START 0
#define OFF_END   (NB*NS)
#define OFF_SPANS (2*NB*NS)
#define OFF_NSP   (2*NB*NS + NB*NL)
#define OFF_SOH   (2*NB*NS + NB*NL + NB*9)
#define OFF_EOH   (3*NB*NS + NB*NL + NB*9)
#define OFF_LAB   (4*NB*NS + NB*NL + NB*9)

// ---------------- Kernel A: start/end logits (memory-bound pass) ----------------
__global__ __launch_bounds__(256) void kA(const float* __restrict__ T,
                                          const float* __restrict__ Ws,
                                          const float* __restrict__ We,
                                          const float* __restrict__ bs,
                                          const float* __restrict__ be,
                                          float* __restrict__ out) {
    int row  = blockIdx.x * 4 + (threadIdx.x >> 6);   // (b*512+s)
    int lane = threadIdx.x & 63;
    const float4* p   = (const float4*)(T + (size_t)row * NH);
    const float4* w4s = (const float4*)Ws;
    const float4* w4e = (const float4*)We;
    float accs = 0.f, acce = 0.f;
#pragma unroll
    for (int c = 0; c < 3; ++c) {
        float4 t = p[lane + c * 64];
        float4 a = w4s[lane + c * 64];
        float4 b = w4e[lane + c * 64];
        accs += t.x * a.x + t.y * a.y + t.z * a.z + t.w * a.w;
        acce += t.x * b.x + t.y * b.y + t.z * b.z + t.w * b.w;
    }
#pragma unroll
    for (int off = 32; off > 0; off >>= 1) {
        accs += __shfl_down(accs, off);
        acce += __shfl_down(acce, off);
    }
    if (lane == 0) {
        out[OFF_START + row] = accs + bs[0];
        out[OFF_END   + row] = acce + be[0];
    }
}

// Register-resident wave top-8 over 512 values (tie -> lower index, matching
// stable lax.top_k). Lane holds values at indices {lane, lane+64, ..., lane+448}.
// Local scan uses strict > over ascending indices; butterfly uses (v desc, i asc).
__device__ __forceinline__ void waveTop8(const float* __restrict__ g, int lane,
                                         int* __restrict__ dst) {
    float v0 = g[lane],       v1 = g[lane + 64],  v2 = g[lane + 128], v3 = g[lane + 192];
    float v4 = g[lane + 256], v5 = g[lane + 320], v6 = g[lane + 384], v7 = g[lane + 448];
#pragma unroll
    for (int r = 0; r < 8; ++r) {
        float bv = v0; int bi = lane;
        if (v1 > bv) { bv = v1; bi = lane + 64; }
        if (v2 > bv) { bv = v2; bi = lane + 128; }
        if (v3 > bv) { bv = v3; bi = lane + 192; }
        if (v4 > bv) { bv = v4; bi = lane + 256; }
        if (v5 > bv) { bv = v5; bi = lane + 320; }
        if (v6 > bv) { bv = v6; bi = lane + 384; }
        if (v7 > bv) { bv = v7; bi = lane + 448; }
#pragma unroll
        for (int off = 32; off > 0; off >>= 1) {
            float ov = __shfl_xor(bv, off);
            int   oi = __shfl_xor(bi, off);
            if (ov > bv || (ov == bv && oi < bi)) { bv = ov; bi = oi; }
        }
        if (lane == 0) dst[r] = bi;
        if      (bi == lane)       v0 = -FLT_MAX;
        else if (bi == lane + 64)  v1 = -FLT_MAX;
        else if (bi == lane + 128) v2 = -FLT_MAX;
        else if (bi == lane + 192) v3 = -FLT_MAX;
        else if (bi == lane + 256) v4 = -FLT_MAX;
        else if (bi == lane + 320) v5 = -FLT_MAX;
        else if (bi == lane + 384) v6 = -FLT_MAX;
        else if (bi == lane + 448) v7 = -FLT_MAX;
    }
}

// ---------------- Kernel B: per-sample heads, top-k, greedy merge ----------------
// Wave 0: top-8 starts. Wave 1: top-8 ends. Waves 2-3: seq-head GEMV. All parallel.
__global__ __launch_bounds__(256) void kB(const float* __restrict__ seq_rep,
                                          const float* __restrict__ W_nspans,
                                          const float* __restrict__ b_nspans,
                                          const float* __restrict__ W_span,
                                          const float* __restrict__ b_span,
                                          float* __restrict__ out,
                                          int* __restrict__ wsI,
                                          float* __restrict__ wsF) {
    int b = blockIdx.x, tid = threadIdx.x;
    __shared__ int   topS[NK], topE[NK];
    __shared__ float part[3][41];
    __shared__ float fl[NL], nsp[9];

    if (tid < 64) {
        waveTop8(out + OFF_START + b * NS, tid, topS);
    } else if (tid < 128) {
        waveTop8(out + OFF_END + b * NS, tid - 64, topE);
    } else if (tid < 251) {
        int t = tid - 128, g = t / 41, l = t % 41;
        int h0 = g * 256;
        const float* sr = seq_rep + b * NH;
        float acc = 0.f;
        if (l < 32) {
            for (int h = h0; h < h0 + 256; ++h) acc += sr[h] * W_span[h * NL + l];
        } else {
            int j = l - 32;
            for (int h = h0; h < h0 + 256; ++h) acc += sr[h] * W_nspans[h * 9 + j];
        }
        part[g][l] = acc;
    }
    __syncthreads();
    if (tid < 41) {
        float a = part[0][tid] + part[1][tid] + part[2][tid];
        if (tid < 32) fl[tid] = a + b_span[tid];
        else          nsp[tid - 32] = a + b_nspans[tid - 32];
    }
    __syncthreads();

    if (tid < 9)  out[OFF_NSP + b * 9 + tid] = nsp[tid];
    if (tid >= 32 && tid < 64) wsF[b * 32 + (tid - 32)] = fl[tid - 32];

    if (tid == 0) {
        // n_spans = argmax over 9 (tie -> lowest index)
        int ns = 0; float bv = nsp[0];
        for (int j = 1; j < 9; ++j) if (nsp[j] > bv) { bv = nsp[j]; ns = j; }

        int ss[NK], es[NK];
        for (int i = 0; i < NK; ++i) {
            ss[i] = (i < ns) ? topS[i] : NS;
            es[i] = (i < ns) ? topE[i] : NS;
        }
        // insertion sort ascending
        for (int i = 1; i < NK; ++i) {
            int v = ss[i], j = i - 1;
            while (j >= 0 && ss[j] > v) { ss[j + 1] = ss[j]; --j; }
            ss[j + 1] = v;
        }
        for (int i = 1; i < NK; ++i) {
            int v = es[i], j = i - 1;
            while (j >= 0 && es[j] > v) { es[j + 1] = es[j]; --j; }
            es[j + 1] = v;
        }
        // faithful greedy merge (matches the while_loop body semantics)
        int sa[NK], ea[NK];
        for (int i = 0; i < NK; ++i) { sa[i] = 0; ea[i] = 0; }
        int si = 0, ei = 0, nrem = ns, last = 0, cnt = 0;
        while (nrem > 0 && si < ns && ei < ns) {
            int s = ss[si], e = es[ei];
            bool take = (e > s) && (s >= last);
            if (take) { sa[cnt] = s; ea[cnt] = e; last = e; ++cnt; --nrem; }
            if (e > s) ++si;
            if (take || e <= s) ++ei;
        }
        // arg_full (labels_single)
        int af = 0; float fv = fl[0];
        for (int l = 1; l < NL; ++l) if (fl[l] > fv) { fv = fl[l]; af = l; }

        int* W = wsI + b * 32;
        W[0] = ns; W[1] = cnt; W[2] = af; W[3] = topS[0]; W[4] = topE[0];
        for (int i = 0; i < NK; ++i) { W[5 + i] = sa[i]; W[13 + i] = ea[i]; }
    }
}

// ---------------- Kernel C: span mean vectors + span logits ----------------
// 8 waves split rows round-robin; float4 loads, 2x unroll (6 loads in flight/wave).
__global__ __launch_bounds__(512) void kC(const float* __restrict__ T,
                                          const float* __restrict__ W_span,
                                          const float* __restrict__ b_span,
                                          const int* __restrict__ wsI,
                                          float* __restrict__ wsLG) {
    int b = blockIdx.x >> 3, k = blockIdx.x & 7, tid = threadIdx.x;
    const int* W = wsI + b * 32;
    int ns = W[0], cnt = W[1];
    if (ns <= 1 || k >= cnt) return;   // uniform per block
    int s = W[5 + k], e = W[13 + k];

    __shared__ float4 sm4[8][192];
    __shared__ float  vec[NH];
    __shared__ float  pl[8][32];

    int wave = tid >> 6, lane = tid & 63;
    float4 a0 = make_float4(0.f, 0.f, 0.f, 0.f), a1 = a0, a2 = a0;
    const float4* Tb = (const float4*)(T + (size_t)b * NS * NH);

    int r = s + wave;
    for (; r + 8 < e; r += 16) {
        const float4* p = Tb + (size_t)r * 192 + lane;
        const float4* q = Tb + (size_t)(r + 8) * 192 + lane;
        float4 x0 = p[0], x1 = p[64], x2 = p[128];
        float4 y0 = q[0], y1 = q[64], y2 = q[128];
        a0.x += x0.x + y0.x; a0.y += x0.y + y0.y; a0.z += x0.z + y0.z; a0.w += x0.w + y0.w;
        a1.x += x1.x + y1.x; a1.y += x1.y + y1.y; a1.z += x1.z + y1.z; a1.w += x1.w + y1.w;
        a2.x += x2.x + y2.x; a2.y += x2.y + y2.y; a2.z += x2.z + y2.z; a2.w += x2.w + y2.w;
    }
    if (r < e) {
        const float4* p = Tb + (size_t)r * 192 + lane;
        float4 x0 = p[0], x1 = p[64], x2 = p[128];
        a0.x += x0.x; a0.y += x0.y; a0.z += x0.z; a0.w += x0.w;
        a1.x += x1.x; a1.y += x1.y; a1.z += x1.z; a1.w += x1.w;
        a2.x += x2.x; a2.y += x2.y; a2.z += x2.z; a2.w += x2.w;
    }
    sm4[wave][lane]       = a0;
    sm4[wave][lane + 64]  = a1;
    sm4[wave][lane + 128] = a2;
    __syncthreads();

    if (tid < 192) {
        float inv = 1.f / (float)(e - s);   // take requires e > s
        float4 v = make_float4(0.f, 0.f, 0.f, 0.f);
#pragma unroll
        for (int w = 0; w < 8; ++w) {
            float4 u = sm4[w][tid];
            v.x += u.x; v.y += u.y; v.z += u.z; v.w += u.w;
        }
        v.x *= inv; v.y *= inv; v.z *= inv; v.w *= inv;
        ((float4*)vec)[tid] = v;
    }
    __syncthreads();

    if (tid < 256) {
        int g = tid >> 5, l = tid & 31;
        float acc = 0.f;
        int h0 = g * 96;
        for (int h = h0; h < h0 + 96; ++h) acc += vec[h] * W_span[h * NL + l];
        pl[g][l] = acc;
    }
    __syncthreads();
    if (tid < 32) {
        float a = b_span[tid];
        for (int gg = 0; gg < 8; ++gg) a += pl[gg][tid];
        wsLG[(b * NK + k) * NL + tid] = a;
    }
}

// ---------------- Kernel D: assemble spans/labels/one-hots ----------------
__global__ __launch_bounds__(512) void kD(const int* __restrict__ wsI,
                                          const float* __restrict__ wsF,
                                          const float* __restrict__ wsLG,
                                          float* __restrict__ out) {
    int b = blockIdx.x, t = threadIdx.x;
    const int* W = wsI + b * 32;
    int ns = W[0], cnt = W[1], af = W[2], as_ = W[3], ae_ = W[4];
    bool multi = ns > 1;
    __shared__ int   sa[NK], ea[NK], sl[NK];
    __shared__ float lgs[NK][NL];
    if (t < NK) { sa[t] = W[5 + t]; ea[t] = W[13 + t]; }
    __syncthreads();
    if (t < NK) {
        if (multi && t < cnt) {
            const float* Lp = wsLG + (b * NK + t) * NL;
            float bv = Lp[0]; int bi = 0;
            for (int l = 0; l < NL; ++l) {
                lgs[t][l] = Lp[l];
                if (Lp[l] > bv) { bv = Lp[l]; bi = l; }
            }
            sl[t] = bi;
        } else sl[t] = -1;
    }
    __syncthreads();
    if (t < NL) {
        float sp, lb;
        if (multi) {
            float mx = 0.f;
            if (cnt > 0) {
                mx = -FLT_MAX;
                for (int k = 0; k < cnt; ++k) mx = fmaxf(mx, lgs[k][t]);
            }
            sp = mx;
            lb = 0.f;
            for (int k = 0; k < cnt; ++k) if (sl[k] == t) lb = 1.f;
        } else {
            sp = wsF[b * NL + t];
            lb = (t == af) ? 1.f : 0.f;
        }
        out[OFF_SPANS + b * NL + t] = sp;
        out[OFF_LAB   + b * NL + t] = lb;
    }
    {
        float svv = 0.f, evv = 0.f;
        if (multi) {
            for (int k = 0; k < cnt; ++k) {
                if (sa[k] == t) svv = 1.f;
                if (ea[k] == t) evv = 1.f;
            }
        } else {
            svv = (t == as_) ? 1.f : 0.f;
            evv = (t == ae_) ? 1.f : 0.f;
        }
        out[OFF_SOH + b * NS + t] = svv;
        out[OFF_EOH + b * NS + t] = evv;
    }
}

extern "C" void kernel_launch(void* const* d_in, const int* in_sizes, int n_in,
                              void* d_out, int out_size, void* d_ws, size_t ws_size,
                              hipStream_t stream) {
    const float* tokens   = (const float*)d_in[0];
    const float* seq_rep  = (const float*)d_in[1];
    const float* W_start  = (const float*)d_in[2];
    const float* b_start  = (const float*)d_in[3];
    const float* W_end    = (const float*)d_in[4];
    const float* b_end    = (const float*)d_in[5];
    const float* W_nspans = (const float*)d_in[6];
    const float* b_nspans = (const float*)d_in[7];
    const float* W_span   = (const float*)d_in[8];
    const float* b_span   = (const float*)d_in[9];
    float* out = (float*)d_out;

    int*   wsI  = (int*)d_ws;                                    // 64*32 ints
    float* wsF  = (float*)((char*)d_ws + NB * 32 * sizeof(int)); // 64*32 floats (full_seq rows)
    float* wsLG = (float*)((char*)d_ws + NB * 32 * sizeof(int) + NB * NL * sizeof(float)); // 64*8*32

    kA<<<(NB * NS) / 4, 256, 0, stream>>>(tokens, W_start, W_end, b_start, b_end, out);
    kB<<<NB, 256, 0, stream>>>(seq_rep, W_nspans, b_nspans, W_span, b_span, out, wsI, wsF);
    kC<<<NB * NK, 512, 0, stream>>>(tokens, W_span, b_span, wsI, wsLG);
    kD<<<NB, 512, 0, stream>>>(wsI, wsF, wsLG, out);
}